// Round 15
// baseline (160.131 us; speedup 1.0000x reference)
//
#include <hip/hip_runtime.h>
#include <stdint.h>

#define FEAT_STRIDE 16
#define PRE_NMS 6000
#define POST_NMS 300
#define NMS_TH 0.7f

static constexpr int B_ = 2, A_ = 9, H_ = 32, W_ = 32, T_ = 16;
static constexpr int LOC = H_ * W_ * T_;   // 16384
static constexpr int N_ = LOC * A_;        // 147456
static constexpr int NBIN = 65536;
static constexpr int NREP = 8;             // histogram replicas (1 per XCD)
static constexpr int CAP = 8192;           // candidate capacity per batch
static constexpr int NW = 94;              // ceil(6000/64) mask words per row
static constexpr int ROWS = 6016;          // NW*64 padded rows

// Exact threshold: fl32(inter/denom) > 0.7f  <=>  inter >= BMID * denom (real),
// BMID = midpoint(0.7f, nextafter(0.7f)); BMID*(double)denom exact (25+24<=53).
static constexpr double BMID = 0.7000000178813934326171875;

// sortedBox row: [x1,y1,z1,x2, y2,z2,vol,score]
// mask TILED layout: maskT[bb][g][w][lane] — tile (g,w) is 64 contiguous words
//   (coalesced store); kept row (g,l): word w at rowBase(g,l) + w*64 u64.
// band: [bb][row][4] = mask words g..g+3 of row (g = row>>6).

__device__ __forceinline__ uint32_t f2u(float f) {
    uint32_t b = __float_as_uint(f);
    return b ^ ((b >> 31) ? 0xFFFFFFFFu : 0x80000000u);
}
__device__ __forceinline__ float u2f(uint32_t u) {
    uint32_t b = (u >> 31) ? (u ^ 0x80000000u) : ~u;
    return __uint_as_float(b);
}
__device__ __forceinline__ unsigned long long rl64(unsigned long long v, int lane) {
    unsigned int lo = (unsigned int)__builtin_amdgcn_readlane((int)(unsigned int)v, lane);
    unsigned int hi = (unsigned int)__builtin_amdgcn_readlane((int)(unsigned int)(v >> 32), lane);
    return ((unsigned long long)hi << 32) | lo;
}

// 1) replicated histogram of score keys' top-16 bits.
__global__ void hist_kernel(const float* __restrict__ scores_map,
                            unsigned int* __restrict__ histR) {
    int gid = blockIdx.x * blockDim.x + threadIdx.x;
    if (gid >= B_ * N_) return;
    int b = gid / N_;
    int r = gid - b * N_;
    int a = r / LOC;
    int loc = r - a * LOC;
    float sc = scores_map[((size_t)(b * 2 * A_ + A_ + a)) * LOC + loc];
    uint32_t u = f2u(sc);
    int rep = blockIdx.x & (NREP - 1);
    atomicAdd(&histR[((size_t)(rep * B_ + b)) * NBIN + (u >> 16)], 1u);
}

// 2a) fold replicas -> canonical counts in hist (coalesced) + chunk partials
__global__ void __launch_bounds__(256) partial_kernel(
        const unsigned int* __restrict__ histR,
        unsigned int* __restrict__ hist,
        unsigned int* __restrict__ partials) {
    int c = blockIdx.x, bb = blockIdx.y, t = threadIdx.x;
    uint4 acc = {0u, 0u, 0u, 0u};
#pragma unroll
    for (int r = 0; r < NREP; ++r) {
        const uint4* h4 = reinterpret_cast<const uint4*>(
            histR + ((size_t)(r * B_ + bb)) * NBIN + c * 1024);
        uint4 v = h4[t];
        acc.x += v.x; acc.y += v.y; acc.z += v.z; acc.w += v.w;
    }
    reinterpret_cast<uint4*>(hist + (size_t)bb * NBIN + c * 1024)[t] = acc;
    __shared__ unsigned int red[256];
    red[t] = acc.x + acc.y + acc.z + acc.w;
    __syncthreads();
    for (int off = 128; off > 0; off >>= 1) {
        if (t < off) red[t] += red[t + off];
        __syncthreads();
    }
    if (t == 0) partials[bb * 64 + c] = red[0];
}

// 2b) folded counts -> suffix offsets (bucket starts) + threshold bin detect
__global__ void __launch_bounds__(256) rewrite_kernel(
        unsigned int* __restrict__ hist,
        unsigned int* __restrict__ binbase,
        const unsigned int* __restrict__ partials,
        unsigned int* __restrict__ thr) {
    int c = blockIdx.x, bb = blockIdx.y, t = threadIdx.x;
    __shared__ unsigned int sp[64];
    __shared__ unsigned int ssum[256];
    if (t < 64) sp[t] = partials[bb * 64 + t];
    unsigned int* h = hist + (size_t)bb * NBIN + c * 1024;
    unsigned int* bs = binbase + (size_t)bb * NBIN + c * 1024;
    uint4 v = reinterpret_cast<const uint4*>(h)[t];
    ssum[t] = v.x + v.y + v.z + v.w;
    __syncthreads();
    unsigned int chunkBase = 0;
    for (int q = c + 1; q < 64; ++q) chunkBase += sp[q];
    for (int off = 1; off < 256; off <<= 1) {
        unsigned int val = (t + off < 256) ? ssum[t + off] : 0u;
        __syncthreads();
        ssum[t] += val;
        __syncthreads();
    }
    unsigned int run = chunkBase + ((t < 255) ? ssum[t + 1] : 0u);
    unsigned int cnt[4] = {v.x, v.y, v.z, v.w};
    unsigned int offv[4];
    for (int q = 3; q >= 0; --q) {
        offv[q] = run;
        unsigned int newrun = run + cnt[q];
        if (run < (unsigned)PRE_NMS && newrun >= (unsigned)PRE_NMS) {
            thr[bb * 2 + 0] = (unsigned)(c * 1024 + t * 4 + q);
            thr[bb * 2 + 1] = newrun;
        }
        run = newrun;
    }
    uint4 o4 = {offv[0], offv[1], offv[2], offv[3]};
    reinterpret_cast<uint4*>(h)[t] = o4;    // bucket cursors
    reinterpret_cast<uint4*>(bs)[t] = o4;   // immutable bucket starts
}

// 3) compact: scatter passing keys into their bin's bucket.
__global__ void __launch_bounds__(256) compact_kernel(
        const float* __restrict__ scores_map,
        const unsigned int* __restrict__ thr,
        unsigned long long* __restrict__ cand,
        unsigned int* __restrict__ hist) {
    int tid = threadIdx.x;
    int gid = blockIdx.x * 256 + tid;
    int b = gid / N_;
    int r = gid - b * N_;
    int a = r / LOC;
    int loc = r - a * LOC;
    float sc = scores_map[((size_t)(b * 2 * A_ + A_ + a)) * LOC + loc];
    uint32_t u = f2u(sc);
    uint32_t bin = u >> 16;
    if (bin >= thr[b * 2]) {
        int n = loc * A_ + a;
        unsigned long long key = ((unsigned long long)u << 18)
                               | (unsigned long long)(N_ - 1 - n);
        unsigned int slot = atomicAdd(&hist[b * NBIN + bin], 1u);
        if (slot < (unsigned)CAP)
            cand[(size_t)b * CAP + slot] = key;
    }
}

// 4) bucket rank + decode: rank = binbase[bin] + (# same-bucket keys greater).
__global__ void __launch_bounds__(256) bucket_decode(
        const unsigned long long* __restrict__ cand,
        const unsigned int* __restrict__ hist,
        const unsigned int* __restrict__ binbase,
        const unsigned int* __restrict__ thr,
        const float* __restrict__ bbox_frame,
        const float* __restrict__ im_info,
        const float* __restrict__ anchors,
        float* __restrict__ sortedBox) {
    int gid = blockIdx.x * 256 + threadIdx.x;
    int bb = gid / CAP;
    int i = gid - bb * CAP;
    int count = (int)thr[bb * 2 + 1];
    if (count > CAP) count = CAP;
    if (i >= count) return;
    const unsigned long long* cb = cand + (size_t)bb * CAP;
    unsigned long long me = cb[i];
    int bin = (int)(me >> 34);
    int start = (int)binbase[bb * NBIN + bin];
    int end = (int)hist[bb * NBIN + bin];
    if (end > count) end = count;
    int rank = start;
    for (int q = start; q < end; ++q)
        rank += (cb[q] > me);
    if (rank >= PRE_NMS) return;

    uint32_t u = (uint32_t)(me >> 18);
    int n = N_ - 1 - (int)(me & 0x3FFFFull);
    int a = n % A_;
    int loc = n / A_;
    int k = loc % T_;
    int j = (loc / T_) % W_;
    int ii = loc / (T_ * W_);

    float ax1 = anchors[a * 6 + 0] + (float)(FEAT_STRIDE * j);
    float ay1 = anchors[a * 6 + 1] + (float)(FEAT_STRIDE * ii);
    float az1 = anchors[a * 6 + 2] + (float)k;
    float ax2 = anchors[a * 6 + 3] + (float)(FEAT_STRIDE * j);
    float ay2 = anchors[a * 6 + 4] + (float)(FEAT_STRIDE * ii);
    float az2 = anchors[a * 6 + 5] + (float)k;
    float aw = ax2 - ax1 + 1.0f, ah = ay2 - ay1 + 1.0f, al = az2 - az1 + 1.0f;
    float acx = ax1 + 0.5f * aw, acy = ay1 + 0.5f * ah, acz = az1 + 0.5f * al;

    const float* dp = bbox_frame + ((size_t)(bb * 6 * A_ + a * 6)) * LOC
                    + ii * (W_ * T_) + j * T_ + k;
    float d0 = dp[0 * LOC], d1 = dp[1 * LOC], d2 = dp[2 * LOC];
    float d3 = dp[3 * LOC], d4 = dp[4 * LOC], d5 = dp[5 * LOC];

    float pcx = d0 * aw + acx, pcy = d1 * ah + acy, pcz = d2 * al + acz;
    float pw = expf(d3) * aw, ph = expf(d4) * ah, pl = expf(d5) * al;

    float x1 = pcx - 0.5f * pw, y1 = pcy - 0.5f * ph, z1 = pcz - 0.5f * pl;
    float x2 = pcx + 0.5f * pw, y2 = pcy + 0.5f * ph, z2 = pcz + 0.5f * pl;

    float lx = im_info[1] - 1.0f, ly = im_info[0] - 1.0f, lz = im_info[2] - 1.0f;
    x1 = fminf(fmaxf(x1, 0.0f), lx); y1 = fminf(fmaxf(y1, 0.0f), ly); z1 = fminf(fmaxf(z1, 0.0f), lz);
    x2 = fminf(fmaxf(x2, 0.0f), lx); y2 = fminf(fmaxf(y2, 0.0f), ly); z2 = fminf(fmaxf(z2, 0.0f), lz);

    float vol = (x2 - x1 + 1.0f) * (y2 - y1 + 1.0f) * (z2 - z1 + 1.0f);
    float* p = sortedBox + ((size_t)bb * ROWS + rank) * 8;
    p[0] = x1; p[1] = y1; p[2] = z1; p[3] = x2;
    p[4] = y2; p[5] = z2; p[6] = vol; p[7] = u2f(u);
}

// 5) IoU bitmask (TILED) + 4-word band per row (words g..g+3).
__global__ void mask_build(const float* __restrict__ sortedBox,
                           unsigned long long* __restrict__ mask,
                           unsigned long long* __restrict__ band) {
    int g = blockIdx.x / NW, w = blockIdx.x % NW;
    if (w < g) return;                      // only upper triangle
    int bb = blockIdx.y;
    int lane = threadIdx.x;                 // 64 threads
    __shared__ float4 colA[64];             // x1, y1, z1, x2
    __shared__ float4 colB[64];             // y2, z2, vol, pad
    const float* sb = sortedBox + (size_t)bb * ROWS * 8;
    int col = w * 64 + lane;
    if (col < PRE_NMS) {
        const float4* cp4 = reinterpret_cast<const float4*>(sb + (size_t)col * 8);
        float4 lo = cp4[0], hi = cp4[1];
        colA[lane] = make_float4(lo.x, lo.y, lo.z, lo.w);
        colB[lane] = make_float4(hi.x, hi.y, hi.z, 0.0f);
    } else {
        colA[lane] = make_float4(3e8f, 0.0f, 0.0f, -3e8f);
        colB[lane] = make_float4(0.0f, 0.0f, 1.0f, 0.0f);
    }
    __syncthreads();
    int row = g * 64 + lane;
    if (row >= PRE_NMS) return;
    const float4* rp4 = reinterpret_cast<const float4*>(sb + (size_t)row * 8);
    float4 rlo = rp4[0], rhi = rp4[1];
    float x1 = rlo.x, y1 = rlo.y, z1 = rlo.z;
    float x2 = rlo.w, y2 = rhi.x, z2 = rhi.y, v = rhi.z;
    unsigned long long word = 0;
#pragma unroll 8
    for (int b2 = 0; b2 < 64; ++b2) {
        float4 cA = colA[b2];
        float4 cB = colB[b2];
        float iw = fminf(x2, cA.w) - fmaxf(x1, cA.x) + 1.0f;
        float ih = fminf(y2, cB.x) - fmaxf(y1, cA.y) + 1.0f;
        float il = fminf(z2, cB.y) - fmaxf(z1, cA.z) + 1.0f;
        iw = fmaxf(iw, 0.0f); ih = fmaxf(ih, 0.0f); il = fmaxf(il, 0.0f);
        float inter = iw * ih * il;
        float denom = v + cB.z - inter;
        bool over = ((double)inter >= BMID * (double)denom);  // exact
        int cidx = w * 64 + b2;
        if (cidx > row && over) word |= (1ull << b2);
    }
    // tiled store: maskT[bb][g][w][lane] — 512B contiguous per block
    mask[(((size_t)bb * NW + g) * NW + w) * 64 + lane] = word;
    unsigned long long* bd = band + ((size_t)bb * ROWS + row) * 4;
    if (w == g) {
        bd[0] = word;
        if (g + 1 >= NW) bd[1] = 0ull;
        if (g + 2 >= NW) bd[2] = 0ull;
        if (g + 3 >= NW) bd[3] = 0ull;
    }
    if (w == g + 1) bd[1] = word;
    if (w == g + 2) bd[2] = word;
    if (w == g + 3) bd[3] = word;
}

// 6) suppress v7 — single wave, register remv (r0/r1), 4-deep STATIC pend
//    pipeline with UNCONDITIONAL loads (dummy slots re-load last kept row —
//    idempotent OR). Exactly 10 VMEM/chunk; consume at c+4 (~1200cy slack).
//    Band regs cover words k..k+3; pend covers >= k+4. Zero inter-wave sync.
__global__ void __launch_bounds__(64) suppress_kernel(
        const unsigned long long* __restrict__ mask,
        const unsigned long long* __restrict__ band,
        const float* __restrict__ sortedBox,
        float* __restrict__ out) {
    int bb = blockIdx.x;
    int lane = threadIdx.x;                 // 64 threads = 1 wave
    __shared__ int keptAll[POST_NMS];

    const unsigned long long* M  = mask + (size_t)bb * NW * NW * 64;
    const unsigned long long* Bd = band + (size_t)bb * ROWS * 4;
    const float* sb = sortedBox + (size_t)bb * ROWS * 8;
    float* ob = out + (size_t)bb * POST_NMS * 7;

    int w1c = lane + 64; if (w1c > NW - 1) w1c = NW - 1;   // clamped 2nd word

    unsigned long long r0 = 0, r1 = 0;
    if (lane == NW - 1 - 64)                // word 93 tail guard (lane 29)
        r1 = ~((1ull << (PRE_NMS - (NW - 1) * 64)) - 1ull);

    unsigned long long pend[4][4][2];
#pragma unroll
    for (int q = 0; q < 4; ++q)
#pragma unroll
        for (int s = 0; s < 4; ++s) { pend[q][s][0] = 0; pend[q][s][1] = 0; }

    unsigned long long bd0[4], bd1[4], bd2[4], bd3[4];
#define BAND_LOAD(CH, BD)                                                      \
    {   const ulonglong2* bp_ = reinterpret_cast<const ulonglong2*>(           \
            &Bd[(size_t)((CH) * 64 + lane) * 4]);                              \
        ulonglong2 vA_ = bp_[0], vB_ = bp_[1];                                 \
        BD[0] = vA_.x; BD[1] = vA_.y; BD[2] = vB_.x; BD[3] = vB_.y; }
    BAND_LOAD(0, bd0)
    BAND_LOAD(1, bd1)
    BAND_LOAD(2, bd2)
    BAND_LOAD(3, bd3)

    unsigned long long supCur = 0, S1 = 0, S2 = 0, S3 = 0;
    const unsigned long long* lastA = M;    // overwritten at chunk 0 (always keeps)
    int kt = 0;
    bool stop = false;

#define CHUNK_BODY(CVAL, PS, BD)                                               \
    if (!stop) {                                                              \
        const int c = (CVAL);                                                 \
        /* consume pend set PS (written at chunk c-4; zero-init for c<4) */   \
        r0 |= pend[PS][0][0] | pend[PS][1][0] | pend[PS][2][0] | pend[PS][3][0]; \
        r1 |= pend[PS][0][1] | pend[PS][1][1] | pend[PS][2][1] | pend[PS][3][1]; \
        unsigned long long cur = (c < 64) ? rl64(r0, c) : rl64(r1, c - 64);   \
        unsigned long long alive = ~(cur | supCur);                           \
        const unsigned long long* a0 = lastA;                                 \
        const unsigned long long* a1 = lastA;                                 \
        const unsigned long long* a2 = lastA;                                 \
        const unsigned long long* a3 = lastA;                                 \
        _Pragma("unroll")                                                      \
        for (int s = 0; s < 4; ++s) {                                          \
            if (alive && kt < POST_NMS) {                                      \
                int b_ = (int)__builtin_ctzll(alive);                          \
                int bs = __builtin_amdgcn_readfirstlane(b_);                   \
                if (lane == 0) keptAll[kt] = c * 64 + bs;                      \
                unsigned long long dr = rl64(BD[0], bs);                       \
                S1 |= rl64(BD[1], bs);                                         \
                S2 |= rl64(BD[2], bs);                                         \
                S3 |= rl64(BD[3], bs);                                         \
                const unsigned long long* rb =                                 \
                    M + ((size_t)c * NW) * 64 + bs;                            \
                if (s == 0) a0 = rb; else if (s == 1) a1 = rb;                 \
                else if (s == 2) a2 = rb; else a3 = rb;                        \
                lastA = rb;                                                    \
                ++kt;                                                          \
                alive &= ~(dr | (1ull << bs));                                 \
            }                                                                  \
        }                                                                      \
        while (alive && kt < POST_NMS) {    /* overflow: immediate OR */       \
            int b_ = (int)__builtin_ctzll(alive);                              \
            int bs = __builtin_amdgcn_readfirstlane(b_);                       \
            if (lane == 0) keptAll[kt] = c * 64 + bs;                          \
            unsigned long long dr = rl64(BD[0], bs);                           \
            S1 |= rl64(BD[1], bs);                                             \
            S2 |= rl64(BD[2], bs);                                             \
            S3 |= rl64(BD[3], bs);                                             \
            const unsigned long long* rb = M + ((size_t)c * NW) * 64 + bs;     \
            r0 |= rb[(size_t)lane * 64];                                       \
            r1 |= rb[(size_t)w1c * 64];                                        \
            lastA = rb;                                                        \
            ++kt;                                                              \
            alive &= ~(dr | (1ull << bs));                                     \
        }                                                                      \
        if (kt >= POST_NMS) stop = true;                                       \
        supCur = S1; S1 = S2; S2 = S3; S3 = 0;                                 \
        /* issue pend loads for set PS (consumed at chunk c+4) */              \
        pend[PS][0][0] = a0[(size_t)lane * 64];                                \
        pend[PS][0][1] = a0[(size_t)w1c * 64];                                 \
        pend[PS][1][0] = a1[(size_t)lane * 64];                                \
        pend[PS][1][1] = a1[(size_t)w1c * 64];                                 \
        pend[PS][2][0] = a2[(size_t)lane * 64];                                \
        pend[PS][2][1] = a2[(size_t)w1c * 64];                                 \
        pend[PS][3][0] = a3[(size_t)lane * 64];                                \
        pend[PS][3][1] = a3[(size_t)w1c * 64];                                 \
        /* band prefetch for chunk c+4 into the set just vacated */            \
        if (c + 4 < NW) BAND_LOAD(c + 4, BD)                                   \
    }

    for (int cb = 0; cb < 92; cb += 4) {
        CHUNK_BODY(cb + 0, 0, bd0)
        CHUNK_BODY(cb + 1, 1, bd1)
        CHUNK_BODY(cb + 2, 2, bd2)
        CHUNK_BODY(cb + 3, 3, bd3)
    }
    CHUNK_BODY(92, 0, bd0)
    CHUNK_BODY(93, 1, bd1)
#undef CHUNK_BODY
#undef BAND_LOAD

    // outputs: [score, x1,y1,z1,x2,y2,z2] from sb row [x1..z2, vol, score]
    for (int e = lane; e < kt * 7; e += 64) {
        int i = e / 7, j = e - i * 7;
        ob[e] = sb[(size_t)keptAll[i] * 8 + (j == 0 ? 7 : j - 1)];
    }
    for (int idx = kt * 7 + lane; idx < POST_NMS * 7; idx += 64)
        ob[idx] = 0.0f;
}

extern "C" void kernel_launch(void* const* d_in, const int* in_sizes, int n_in,
                              void* d_out, int out_size, void* d_ws, size_t ws_size,
                              hipStream_t stream) {
    const float* scores_map = (const float*)d_in[0];
    const float* bbox_frame = (const float*)d_in[1];
    const float* im_info    = (const float*)d_in[2];
    const float* anchors    = (const float*)d_in[3];
    float* out = (float*)d_out;

    // workspace layout (bytes) — total 10,088,976 (same footprint)
    char* ws = (char*)d_ws;
    unsigned long long* mask  = (unsigned long long*)(ws + 0);          // 9,048,064
    unsigned int* binbase     = (unsigned int*)(ws + 0);                // aliases mask
    unsigned int* histR       = (unsigned int*)(ws + 524288);           // aliases mask: 4,194,304
    float* sortedBox          = (float*)(ws + 9048064);                 // 385,024
    unsigned long long* cand  = (unsigned long long*)(ws + 9433088);    // 131,072
    unsigned int* hist        = (unsigned int*)(ws + 9564160);          // 524,288 canonical
    unsigned long long* band  = (unsigned long long*)(ws + 9564160);    // aliases hist
                                                                        // (hist dead after decode) 385,024
    unsigned int* thr         = (unsigned int*)(ws + 10088448);         // 16
    unsigned int* partials    = (unsigned int*)(ws + 10088464);         // 512

    hipMemsetAsync(histR, 0, (size_t)NREP * B_ * NBIN * 4, stream);

    int total = B_ * N_;
    hist_kernel<<<(total + 255) / 256, 256, 0, stream>>>(scores_map, histR);
    partial_kernel<<<dim3(64, B_), 256, 0, stream>>>(histR, hist, partials);
    rewrite_kernel<<<dim3(64, B_), 256, 0, stream>>>(hist, binbase, partials, thr);
    compact_kernel<<<total / 256, 256, 0, stream>>>(scores_map, thr, cand, hist);
    bucket_decode<<<B_ * CAP / 256, 256, 0, stream>>>(cand, hist, binbase, thr,
                                                      bbox_frame, im_info, anchors,
                                                      sortedBox);
    mask_build<<<dim3(NW * NW, B_), 64, 0, stream>>>(sortedBox, mask, band);
    suppress_kernel<<<B_, 64, 0, stream>>>(mask, band, sortedBox, out);
}

// Round 16
// 136.865 us; speedup vs baseline: 1.1700x; 1.1700x over previous
//
#include <hip/hip_runtime.h>
#include <stdint.h>

#define FEAT_STRIDE 16
#define PRE_NMS 6000
#define POST_NMS 300
#define NMS_TH 0.7f

static constexpr int B_ = 2, A_ = 9, H_ = 32, W_ = 32, T_ = 16;
static constexpr int LOC = H_ * W_ * T_;   // 16384
static constexpr int N_ = LOC * A_;        // 147456
static constexpr int NBIN = 65536;
static constexpr int NREP = 8;             // histogram replicas (1 per XCD)
static constexpr int CAP = 8192;           // candidate capacity per batch
static constexpr int NW = 94;              // ceil(6000/64) mask words per row
static constexpr int ROWS = 6016;          // NW*64 padded rows

// Exact threshold: fl32(inter/denom) > 0.7f  <=>  inter >= BMID * denom (real),
// BMID = midpoint(0.7f, nextafter(0.7f)); BMID*(double)denom exact (25+24<=53).
static constexpr double BMID = 0.7000000178813934326171875;

// sortedBox row: [x1,y1,z1,x2, y2,z2,vol,score]; mask: [bb][w][row] transposed.
// band: [bb][row][4] = mask words g..g+3 of row (g = row>>6).

__device__ __forceinline__ uint32_t f2u(float f) {
    uint32_t b = __float_as_uint(f);
    return b ^ ((b >> 31) ? 0xFFFFFFFFu : 0x80000000u);
}
__device__ __forceinline__ float u2f(uint32_t u) {
    uint32_t b = (u >> 31) ? (u ^ 0x80000000u) : ~u;
    return __uint_as_float(b);
}
__device__ __forceinline__ unsigned long long rl64(unsigned long long v, int lane) {
    unsigned int lo = (unsigned int)__builtin_amdgcn_readlane((int)(unsigned int)v, lane);
    unsigned int hi = (unsigned int)__builtin_amdgcn_readlane((int)(unsigned int)(v >> 32), lane);
    return ((unsigned long long)hi << 32) | lo;
}

// 1) replicated histogram of score keys' top-16 bits.
__global__ void hist_kernel(const float* __restrict__ scores_map,
                            unsigned int* __restrict__ histR) {
    int gid = blockIdx.x * blockDim.x + threadIdx.x;
    if (gid >= B_ * N_) return;
    int b = gid / N_;
    int r = gid - b * N_;
    int a = r / LOC;
    int loc = r - a * LOC;
    float sc = scores_map[((size_t)(b * 2 * A_ + A_ + a)) * LOC + loc];
    uint32_t u = f2u(sc);
    int rep = blockIdx.x & (NREP - 1);
    atomicAdd(&histR[((size_t)(rep * B_ + b)) * NBIN + (u >> 16)], 1u);
}

// 2a) fold replicas -> canonical counts in hist (coalesced) + chunk partials
__global__ void __launch_bounds__(256) partial_kernel(
        const unsigned int* __restrict__ histR,
        unsigned int* __restrict__ hist,
        unsigned int* __restrict__ partials) {
    int c = blockIdx.x, bb = blockIdx.y, t = threadIdx.x;
    uint4 acc = {0u, 0u, 0u, 0u};
#pragma unroll
    for (int r = 0; r < NREP; ++r) {
        const uint4* h4 = reinterpret_cast<const uint4*>(
            histR + ((size_t)(r * B_ + bb)) * NBIN + c * 1024);
        uint4 v = h4[t];
        acc.x += v.x; acc.y += v.y; acc.z += v.z; acc.w += v.w;
    }
    reinterpret_cast<uint4*>(hist + (size_t)bb * NBIN + c * 1024)[t] = acc;
    __shared__ unsigned int red[256];
    red[t] = acc.x + acc.y + acc.z + acc.w;
    __syncthreads();
    for (int off = 128; off > 0; off >>= 1) {
        if (t < off) red[t] += red[t + off];
        __syncthreads();
    }
    if (t == 0) partials[bb * 64 + c] = red[0];
}

// 2b) folded counts -> suffix offsets (bucket starts) + threshold bin detect
__global__ void __launch_bounds__(256) rewrite_kernel(
        unsigned int* __restrict__ hist,
        unsigned int* __restrict__ binbase,
        const unsigned int* __restrict__ partials,
        unsigned int* __restrict__ thr) {
    int c = blockIdx.x, bb = blockIdx.y, t = threadIdx.x;
    __shared__ unsigned int sp[64];
    __shared__ unsigned int ssum[256];
    if (t < 64) sp[t] = partials[bb * 64 + t];
    unsigned int* h = hist + (size_t)bb * NBIN + c * 1024;
    unsigned int* bs = binbase + (size_t)bb * NBIN + c * 1024;
    uint4 v = reinterpret_cast<const uint4*>(h)[t];
    ssum[t] = v.x + v.y + v.z + v.w;
    __syncthreads();
    unsigned int chunkBase = 0;
    for (int q = c + 1; q < 64; ++q) chunkBase += sp[q];
    for (int off = 1; off < 256; off <<= 1) {
        unsigned int val = (t + off < 256) ? ssum[t + off] : 0u;
        __syncthreads();
        ssum[t] += val;
        __syncthreads();
    }
    unsigned int run = chunkBase + ((t < 255) ? ssum[t + 1] : 0u);
    unsigned int cnt[4] = {v.x, v.y, v.z, v.w};
    unsigned int offv[4];
    for (int q = 3; q >= 0; --q) {
        offv[q] = run;
        unsigned int newrun = run + cnt[q];
        if (run < (unsigned)PRE_NMS && newrun >= (unsigned)PRE_NMS) {
            thr[bb * 2 + 0] = (unsigned)(c * 1024 + t * 4 + q);
            thr[bb * 2 + 1] = newrun;
        }
        run = newrun;
    }
    uint4 o4 = {offv[0], offv[1], offv[2], offv[3]};
    reinterpret_cast<uint4*>(h)[t] = o4;    // bucket cursors
    reinterpret_cast<uint4*>(bs)[t] = o4;   // immutable bucket starts
}

// 3) compact: scatter passing keys into their bin's bucket.
__global__ void __launch_bounds__(256) compact_kernel(
        const float* __restrict__ scores_map,
        const unsigned int* __restrict__ thr,
        unsigned long long* __restrict__ cand,
        unsigned int* __restrict__ hist) {
    int tid = threadIdx.x;
    int gid = blockIdx.x * 256 + tid;
    int b = gid / N_;
    int r = gid - b * N_;
    int a = r / LOC;
    int loc = r - a * LOC;
    float sc = scores_map[((size_t)(b * 2 * A_ + A_ + a)) * LOC + loc];
    uint32_t u = f2u(sc);
    uint32_t bin = u >> 16;
    if (bin >= thr[b * 2]) {
        int n = loc * A_ + a;
        unsigned long long key = ((unsigned long long)u << 18)
                               | (unsigned long long)(N_ - 1 - n);
        unsigned int slot = atomicAdd(&hist[b * NBIN + bin], 1u);
        if (slot < (unsigned)CAP)
            cand[(size_t)b * CAP + slot] = key;
    }
}

// 4) bucket rank + decode: rank = binbase[bin] + (# same-bucket keys greater).
__global__ void __launch_bounds__(256) bucket_decode(
        const unsigned long long* __restrict__ cand,
        const unsigned int* __restrict__ hist,
        const unsigned int* __restrict__ binbase,
        const unsigned int* __restrict__ thr,
        const float* __restrict__ bbox_frame,
        const float* __restrict__ im_info,
        const float* __restrict__ anchors,
        float* __restrict__ sortedBox) {
    int gid = blockIdx.x * 256 + threadIdx.x;
    int bb = gid / CAP;
    int i = gid - bb * CAP;
    int count = (int)thr[bb * 2 + 1];
    if (count > CAP) count = CAP;
    if (i >= count) return;
    const unsigned long long* cb = cand + (size_t)bb * CAP;
    unsigned long long me = cb[i];
    int bin = (int)(me >> 34);
    int start = (int)binbase[bb * NBIN + bin];
    int end = (int)hist[bb * NBIN + bin];
    if (end > count) end = count;
    int rank = start;
    for (int q = start; q < end; ++q)
        rank += (cb[q] > me);
    if (rank >= PRE_NMS) return;

    uint32_t u = (uint32_t)(me >> 18);
    int n = N_ - 1 - (int)(me & 0x3FFFFull);
    int a = n % A_;
    int loc = n / A_;
    int k = loc % T_;
    int j = (loc / T_) % W_;
    int ii = loc / (T_ * W_);

    float ax1 = anchors[a * 6 + 0] + (float)(FEAT_STRIDE * j);
    float ay1 = anchors[a * 6 + 1] + (float)(FEAT_STRIDE * ii);
    float az1 = anchors[a * 6 + 2] + (float)k;
    float ax2 = anchors[a * 6 + 3] + (float)(FEAT_STRIDE * j);
    float ay2 = anchors[a * 6 + 4] + (float)(FEAT_STRIDE * ii);
    float az2 = anchors[a * 6 + 5] + (float)k;
    float aw = ax2 - ax1 + 1.0f, ah = ay2 - ay1 + 1.0f, al = az2 - az1 + 1.0f;
    float acx = ax1 + 0.5f * aw, acy = ay1 + 0.5f * ah, acz = az1 + 0.5f * al;

    const float* dp = bbox_frame + ((size_t)(bb * 6 * A_ + a * 6)) * LOC
                    + ii * (W_ * T_) + j * T_ + k;
    float d0 = dp[0 * LOC], d1 = dp[1 * LOC], d2 = dp[2 * LOC];
    float d3 = dp[3 * LOC], d4 = dp[4 * LOC], d5 = dp[5 * LOC];

    float pcx = d0 * aw + acx, pcy = d1 * ah + acy, pcz = d2 * al + acz;
    float pw = expf(d3) * aw, ph = expf(d4) * ah, pl = expf(d5) * al;

    float x1 = pcx - 0.5f * pw, y1 = pcy - 0.5f * ph, z1 = pcz - 0.5f * pl;
    float x2 = pcx + 0.5f * pw, y2 = pcy + 0.5f * ph, z2 = pcz + 0.5f * pl;

    float lx = im_info[1] - 1.0f, ly = im_info[0] - 1.0f, lz = im_info[2] - 1.0f;
    x1 = fminf(fmaxf(x1, 0.0f), lx); y1 = fminf(fmaxf(y1, 0.0f), ly); z1 = fminf(fmaxf(z1, 0.0f), lz);
    x2 = fminf(fmaxf(x2, 0.0f), lx); y2 = fminf(fmaxf(y2, 0.0f), ly); z2 = fminf(fmaxf(z2, 0.0f), lz);

    float vol = (x2 - x1 + 1.0f) * (y2 - y1 + 1.0f) * (z2 - z1 + 1.0f);
    float* p = sortedBox + ((size_t)bb * ROWS + rank) * 8;
    p[0] = x1; p[1] = y1; p[2] = z1; p[3] = x2;
    p[4] = y2; p[5] = z2; p[6] = vol; p[7] = u2f(u);
}

// 5) IoU bitmask (transposed [w][row]) + 4-word band per row (words g..g+3).
__global__ void mask_build(const float* __restrict__ sortedBox,
                           unsigned long long* __restrict__ mask,
                           unsigned long long* __restrict__ band) {
    int g = blockIdx.x / NW, w = blockIdx.x % NW;
    if (w < g) return;                      // only upper triangle
    int bb = blockIdx.y;
    int lane = threadIdx.x;                 // 64 threads
    __shared__ float4 colA[64];             // x1, y1, z1, x2
    __shared__ float4 colB[64];             // y2, z2, vol, pad
    const float* sb = sortedBox + (size_t)bb * ROWS * 8;
    int col = w * 64 + lane;
    if (col < PRE_NMS) {
        const float4* cp4 = reinterpret_cast<const float4*>(sb + (size_t)col * 8);
        float4 lo = cp4[0], hi = cp4[1];
        colA[lane] = make_float4(lo.x, lo.y, lo.z, lo.w);
        colB[lane] = make_float4(hi.x, hi.y, hi.z, 0.0f);
    } else {
        colA[lane] = make_float4(3e8f, 0.0f, 0.0f, -3e8f);
        colB[lane] = make_float4(0.0f, 0.0f, 1.0f, 0.0f);
    }
    __syncthreads();
    int row = g * 64 + lane;
    if (row >= PRE_NMS) return;
    const float4* rp4 = reinterpret_cast<const float4*>(sb + (size_t)row * 8);
    float4 rlo = rp4[0], rhi = rp4[1];
    float x1 = rlo.x, y1 = rlo.y, z1 = rlo.z;
    float x2 = rlo.w, y2 = rhi.x, z2 = rhi.y, v = rhi.z;
    unsigned long long word = 0;
#pragma unroll 8
    for (int b2 = 0; b2 < 64; ++b2) {
        float4 cA = colA[b2];
        float4 cB = colB[b2];
        float iw = fminf(x2, cA.w) - fmaxf(x1, cA.x) + 1.0f;
        float ih = fminf(y2, cB.x) - fmaxf(y1, cA.y) + 1.0f;
        float il = fminf(z2, cB.y) - fmaxf(z1, cA.z) + 1.0f;
        iw = fmaxf(iw, 0.0f); ih = fmaxf(ih, 0.0f); il = fmaxf(il, 0.0f);
        float inter = iw * ih * il;
        float denom = v + cB.z - inter;
        bool over = ((double)inter >= BMID * (double)denom);  // exact
        int cidx = w * 64 + b2;
        if (cidx > row && over) word |= (1ull << b2);
    }
    mask[((size_t)bb * NW + w) * ROWS + row] = word;   // coalesced per block
    unsigned long long* bd = band + ((size_t)bb * ROWS + row) * 4;
    if (w == g) {
        bd[0] = word;
        if (g + 1 >= NW) bd[1] = 0ull;
        if (g + 2 >= NW) bd[2] = 0ull;
        if (g + 3 >= NW) bd[3] = 0ull;
    }
    if (w == g + 1) bd[1] = word;
    if (w == g + 2) bd[2] = word;
    if (w == g + 3) bd[3] = word;
}

// 6) suppress v8 — round-10 structure with 128-row PAIRS (47 iterations).
//    wave0 scans words 2p,2p+1 (band regs dA/dB cover words 2p..2p+3;
//    cross-word + next-pair suppression in registers S10/S11); waves 1..15
//    apply pair-(p-1) keeps to remv[w >= 2p+2] + write their outputs.
//    One barrier per pair.
__global__ void __launch_bounds__(1024) suppress_kernel(
        const unsigned long long* __restrict__ mask,
        const unsigned long long* __restrict__ band,
        const float* __restrict__ sortedBox,
        float* __restrict__ out) {
    int bb = blockIdx.x;
    int tid = threadIdx.x;
    int lane = tid & 63;
    __shared__ unsigned long long remv[NW];
    __shared__ int kr[2][128];
    __shared__ int s_nk;
    for (int i = tid; i < NW; i += 1024) remv[i] = 0ull;
    if (tid == 0) {
        remv[NW - 1] = ~((1ull << (PRE_NMS - (NW - 1) * 64)) - 1ull);
        s_nk = 0;
    }
    __syncthreads();

    const unsigned long long* M  = mask + (size_t)bb * NW * ROWS;
    const unsigned long long* Bd = band + (size_t)bb * ROWS * 4;
    const float* sb = sortedBox + (size_t)bb * ROWS * 8;
    float* ob = out + (size_t)bb * POST_NMS * 7;

    int kept_total = 0, prev_nk = 0, prev_base = 0, cur = 0;
    unsigned long long dA0 = 0, dA1 = 0, dA2 = 0, dA3 = 0;
    unsigned long long dB0 = 0, dB1 = 0, dB2 = 0, dB3 = 0;
    unsigned long long sup0 = 0, sup1 = 0;
    if (tid < 64) {                         // prologue: pair-0 bands
        const ulonglong2* bp = reinterpret_cast<const ulonglong2*>(&Bd[(size_t)lane * 4]);
        ulonglong2 u0 = bp[0], u1 = bp[1];
        dA0 = u0.x; dA1 = u0.y; dA2 = u1.x; dA3 = u1.y;
        const ulonglong2* bq = reinterpret_cast<const ulonglong2*>(&Bd[(size_t)(64 + lane) * 4]);
        ulonglong2 v0 = bq[0], v1 = bq[1];
        dB0 = v0.x; dB1 = v0.y; dB2 = v1.x; dB3 = v1.y;
    }

    const int NP = NW / 2;                  // 47 pairs
    for (int p = 0; p < NP; ++p) {
        int w0 = 2 * p, w1 = 2 * p + 1;
        if (tid < 64) {
            unsigned long long nA0 = 0, nA1 = 0, nA2 = 0, nA3 = 0;
            unsigned long long nB0 = 0, nB1 = 0, nB2 = 0, nB3 = 0;
            if (p + 1 < NP) {               // prefetch next pair's bands
                const ulonglong2* bp2 = reinterpret_cast<const ulonglong2*>(
                    &Bd[(size_t)((w0 + 2) * 64 + lane) * 4]);
                ulonglong2 u0 = bp2[0], u1 = bp2[1];
                nA0 = u0.x; nA1 = u0.y; nA2 = u1.x; nA3 = u1.y;
                const ulonglong2* bq2 = reinterpret_cast<const ulonglong2*>(
                    &Bd[(size_t)((w0 + 3) * 64 + lane) * 4]);
                ulonglong2 v0 = bq2[0], v1 = bq2[1];
                nB0 = v0.x; nB1 = v0.y; nB2 = v1.x; nB3 = v1.y;
            }
            unsigned long long S10 = 0, S11 = 0, w1sup = 0;
            int nk = 0;
            // scan word w0 (rows w0*64..+63)
            unsigned long long alive = ~(remv[w0] | sup0);
            while (alive && kept_total + nk < POST_NMS) {
                int b_ = (int)__builtin_ctzll(alive);
                int bs = __builtin_amdgcn_readfirstlane(b_);
                if (lane == 0) kr[cur][nk] = w0 * 64 + bs;
                ++nk;
                unsigned long long dr = rl64(dA0, bs);
                w1sup |= rl64(dA1, bs);      // word w1
                S10   |= rl64(dA2, bs);      // word 2p+2
                S11   |= rl64(dA3, bs);      // word 2p+3
                alive &= ~(dr | (1ull << bs));
            }
            // scan word w1 (rows w1*64..+63)
            alive = ~(remv[w1] | sup1 | w1sup);
            while (alive && kept_total + nk < POST_NMS) {
                int b_ = (int)__builtin_ctzll(alive);
                int bs = __builtin_amdgcn_readfirstlane(b_);
                if (lane == 0) kr[cur][nk] = w1 * 64 + bs;
                ++nk;
                unsigned long long dr = rl64(dB0, bs);
                S10 |= rl64(dB1, bs);        // word 2p+2
                S11 |= rl64(dB2, bs);        // word 2p+3
                alive &= ~(dr | (1ull << bs));
            }
            if (lane == 0) s_nk = nk;
            sup0 = S10; sup1 = S11;
            dA0 = nA0; dA1 = nA1; dA2 = nA2; dA3 = nA3;
            dB0 = nB0; dB1 = nB1; dB2 = nB2; dB3 = nB3;
        } else {
            // bg: apply pair-(p-1) keeps to remv[w >= 2p+2], write their outputs
            int t = tid - 64;
            for (int w2 = w0 + 2 + t; w2 < NW; w2 += 960) {
                unsigned long long v = remv[w2];
                for (int i = 0; i < prev_nk; ++i)
                    v |= M[(size_t)w2 * ROWS + kr[cur ^ 1][i]];
                remv[w2] = v;
            }
            for (int e = t; e < prev_nk * 7; e += 960) {
                int i = e / 7, j = e - i * 7;
                ob[(size_t)(prev_base + i) * 7 + j] =
                    sb[(size_t)kr[cur ^ 1][i] * 8 + (j == 0 ? 7 : j - 1)];
            }
        }
        __syncthreads();
        int nk = s_nk;
        prev_base = kept_total;
        kept_total += nk;
        prev_nk = nk;
        cur ^= 1;
        if (kept_total >= POST_NMS) break;
    }
    // flush outputs of the final scanned pair (its bg pass never ran)
    for (int e = tid; e < prev_nk * 7; e += 1024) {
        int i = e / 7, j = e - i * 7;
        ob[(size_t)(prev_base + i) * 7 + j] =
            sb[(size_t)kr[cur ^ 1][i] * 8 + (j == 0 ? 7 : j - 1)];
    }
    for (int idx = kept_total * 7 + tid; idx < POST_NMS * 7; idx += 1024)
        ob[idx] = 0.0f;
}

extern "C" void kernel_launch(void* const* d_in, const int* in_sizes, int n_in,
                              void* d_out, int out_size, void* d_ws, size_t ws_size,
                              hipStream_t stream) {
    const float* scores_map = (const float*)d_in[0];
    const float* bbox_frame = (const float*)d_in[1];
    const float* im_info    = (const float*)d_in[2];
    const float* anchors    = (const float*)d_in[3];
    float* out = (float*)d_out;

    // workspace layout (bytes) — total 10,088,976 (same footprint)
    char* ws = (char*)d_ws;
    unsigned long long* mask  = (unsigned long long*)(ws + 0);          // 9,048,064
    unsigned int* binbase     = (unsigned int*)(ws + 0);                // aliases mask
    unsigned int* histR       = (unsigned int*)(ws + 524288);           // aliases mask: 4,194,304
    float* sortedBox          = (float*)(ws + 9048064);                 // 385,024
    unsigned long long* cand  = (unsigned long long*)(ws + 9433088);    // 131,072
    unsigned int* hist        = (unsigned int*)(ws + 9564160);          // 524,288 canonical
    unsigned long long* band  = (unsigned long long*)(ws + 9564160);    // aliases hist
                                                                        // (hist dead after decode) 385,024
    unsigned int* thr         = (unsigned int*)(ws + 10088448);         // 16
    unsigned int* partials    = (unsigned int*)(ws + 10088464);         // 512

    hipMemsetAsync(histR, 0, (size_t)NREP * B_ * NBIN * 4, stream);

    int total = B_ * N_;
    hist_kernel<<<(total + 255) / 256, 256, 0, stream>>>(scores_map, histR);
    partial_kernel<<<dim3(64, B_), 256, 0, stream>>>(histR, hist, partials);
    rewrite_kernel<<<dim3(64, B_), 256, 0, stream>>>(hist, binbase, partials, thr);
    compact_kernel<<<total / 256, 256, 0, stream>>>(scores_map, thr, cand, hist);
    bucket_decode<<<B_ * CAP / 256, 256, 0, stream>>>(cand, hist, binbase, thr,
                                                      bbox_frame, im_info, anchors,
                                                      sortedBox);
    mask_build<<<dim3(NW * NW, B_), 64, 0, stream>>>(sortedBox, mask, band);
    suppress_kernel<<<B_, 1024, 0, stream>>>(mask, band, sortedBox, out);
}